// Round 8
// baseline (175.234 us; speedup 1.0000x reference)
//
#include <hip/hip_runtime.h>
#include <cstdint>
#include <cstddef>

#define HD 64
#define NH 16
#define BATCH 2
#define SEQ 2048
#define DIM 1024
#define SCALE 0.03125f   // 1024^-0.5
#define LOG2E 1.4426950408889634f
#define QSCALE (SCALE * LOG2E)   // folded into q at QKV epilogue
#define NT (SEQ / 64)             // 32 KV tiles

typedef short bf16x8 __attribute__((ext_vector_type(8)));
typedef float f32x4 __attribute__((ext_vector_type(4)));
typedef float f32x16 __attribute__((ext_vector_type(16)));
typedef unsigned u32x4 __attribute__((ext_vector_type(4)));

// global_load_lds, 16B per lane; LDS dest = wave-uniform base + lane*16
#define GL16(gp, lp) __builtin_amdgcn_global_load_lds( \
    (const __attribute__((address_space(1))) unsigned int*)(gp), \
    (__attribute__((address_space(3))) unsigned int*)(lp), 16, 0, 0)

static __device__ __forceinline__ unsigned short f2bf(float f) {
  union { float f; unsigned u; } a; a.f = f;
  unsigned r = a.u + 0x7fffu + ((a.u >> 16) & 1u);  // RNE
  return (unsigned short)(r >> 16);
}

static __device__ __forceinline__ f32x4 zero4() {
  f32x4 z; z[0] = 0.f; z[1] = 0.f; z[2] = 0.f; z[3] = 0.f; return z;
}

// ---------------- fp32 -> bf16 convert (vectorized) ----------------
__global__ void convert_x(const float* __restrict__ in, unsigned short* __restrict__ out, int n4) {
  int i = blockIdx.x * blockDim.x + threadIdx.x;
  if (i < n4) {
    float4 v = reinterpret_cast<const float4*>(in)[i];
    ushort4 o;
    o.x = f2bf(v.x); o.y = f2bf(v.y); o.z = f2bf(v.z); o.w = f2bf(v.w);
    reinterpret_cast<ushort4*>(out)[i] = o;
  }
}

// ---------------- transpose + convert: in[R][C] fp32 -> out[C][R] bf16 ----------------
__global__ void transpose_convert(const float* __restrict__ in, unsigned short* __restrict__ out,
                                  int R, int C) {
  __shared__ float tile[32][33];
  int bx = blockIdx.x * 32;
  int by = blockIdx.y * 32;
  int tx = threadIdx.x, ty = threadIdx.y;  // block (32,8)
  #pragma unroll
  for (int i = 0; i < 32; i += 8)
    tile[ty + i][tx] = in[(size_t)(by + ty + i) * C + bx + tx];
  __syncthreads();
  #pragma unroll
  for (int i = 0; i < 32; i += 8)
    out[(size_t)(bx + ty + i) * R + by + tx] = f2bf(tile[tx][ty + i]);
}

// ------- GEMM 128x128 tile (m97-style, global_load_lds): C = A * Bt^T --------
// mode 0: scatter epilogue into q (pre-scaled)/k [B,H,N,hd] and v TRANSPOSED [B,H,hd,N]
// mode 1: fp32 epilogue into outf [M][DIM] (+bias)
__global__ __launch_bounds__(256) void gemm128(
    const unsigned short* __restrict__ A, const unsigned short* __restrict__ Bt,
    const float* __restrict__ bias, int K, int mode,
    unsigned short* __restrict__ qo, unsigned short* __restrict__ ko,
    unsigned short* __restrict__ vo, float* __restrict__ outf) {
  __shared__ __attribute__((aligned(16))) unsigned short As[128 * 64];
  __shared__ __attribute__((aligned(16))) unsigned short Bs[128 * 64];
  const int tid = threadIdx.x;
  const int lane = tid & 63, w = tid >> 6;
  const int lo = lane & 15, hi = lane >> 4;
  const int wm = w >> 1, wn = w & 1;
  // XCD-aware swizzle (T1): nwg % 8 == 0 for both call sites
  const int gx = gridDim.x;
  const int nwg = gx * gridDim.y;
  const int flat = blockIdx.y * gx + blockIdx.x;
  const int swz = (flat & 7) * (nwg >> 3) + (flat >> 3);
  const int m0 = (swz / gx) * 128, n0 = (swz % gx) * 128;
  const int srow = tid >> 3, scol = (tid & 7) * 8;
  const unsigned short* abase = A + (size_t)(m0 + srow) * K + scol;
  const unsigned short* bbase = Bt + (size_t)(n0 + srow) * K + scol;

  f32x4 acc[4][4];
  #pragma unroll
  for (int mr = 0; mr < 4; ++mr)
    #pragma unroll
    for (int nr = 0; nr < 4; ++nr) acc[mr][nr] = zero4();

  const int nkt = K / 64;
  for (int kt = 0; kt < nkt; ++kt) {
    const unsigned short* ak = abase + kt * 64;
    const unsigned short* bk = bbase + kt * 64;
    #pragma unroll
    for (int i = 0; i < 4; ++i) {
      GL16(ak + (size_t)(32 * i) * K, &As[(w * 64 + 256 * i) * 8]);
      GL16(bk + (size_t)(32 * i) * K, &Bs[(w * 64 + 256 * i) * 8]);
    }
    __syncthreads();
    __builtin_amdgcn_s_setprio(1);
    #pragma unroll
    for (int kc = 0; kc < 2; ++kc) {
      bf16x8 af[4], bfr[4];
      #pragma unroll
      for (int mr = 0; mr < 4; ++mr)
        af[mr] = *reinterpret_cast<const bf16x8*>(
            &As[(wm * 64 + mr * 16 + lo) * 64 + kc * 32 + hi * 8]);
      #pragma unroll
      for (int nr = 0; nr < 4; ++nr)
        bfr[nr] = *reinterpret_cast<const bf16x8*>(
            &Bs[(wn * 64 + nr * 16 + lo) * 64 + kc * 32 + hi * 8]);
      #pragma unroll
      for (int mr = 0; mr < 4; ++mr)
        #pragma unroll
        for (int nr = 0; nr < 4; ++nr)
          acc[mr][nr] = __builtin_amdgcn_mfma_f32_16x16x32_bf16(af[mr], bfr[nr], acc[mr][nr], 0, 0, 0);
    }
    __builtin_amdgcn_s_setprio(0);
    __syncthreads();
  }

  #pragma unroll
  for (int nr = 0; nr < 4; ++nr) {
    const int gcol = n0 + wn * 64 + nr * 16 + lo;
    const float bv = bias[gcol];
    #pragma unroll
    for (int mr = 0; mr < 4; ++mr)
      #pragma unroll
      for (int j = 0; j < 4; ++j) {
        const int grow = m0 + wm * 64 + mr * 16 + hi * 4 + j;
        float val = acc[mr][nr][j] + bv;
        if (mode == 0) {
          int which = gcol >> 10;         // 0=q 1=k 2=v
          int hh = (gcol >> 6) & 15;
          int d = gcol & 63;
          int bb = grow >> 11;
          int n = grow & 2047;
          if (which == 0) {
            qo[((size_t)(bb * NH + hh) * SEQ + n) * HD + d] = f2bf(val * QSCALE);
          } else if (which == 1) {
            ko[((size_t)(bb * NH + hh) * SEQ + n) * HD + d] = f2bf(val);
          } else {
            vo[((size_t)(bb * NH + hh) * HD + d) * SEQ + n] = f2bf(val);  // [B,H,hd,N]
          }
        } else {
          outf[(size_t)grow * DIM + gcol] = val;
        }
      }
  }
}

// ------- flash attention, 32x32 MFMA, T15 software pipeline ---------------------------
// grid: (SEQ/128) * B*H = 512 blocks; block 256 threads (4 waves, 32 q-rows each).
// Pipeline: iter t overlaps QK(t+1) (MFMA, result unused until next iter) with
// softmax(t) (VALU) and PV(t). K staged 2 ahead, V 1 ahead; ONE barrier per iter.
// launch_bounds(256,2): VGPR cap 256 (NOT tighter -> spill disaster, R6 lesson).
__global__ __launch_bounds__(256, 2) void attn_kernel(
    const unsigned short* __restrict__ qb, const unsigned short* __restrict__ kb,
    const unsigned short* __restrict__ vtb, const float* __restrict__ gamma,
    const float* __restrict__ dist, unsigned short* __restrict__ ab) {
  // K/V tiles: XOR-swizzled layout, 128B rows, double-buffered (32 KiB total).
  __shared__ __attribute__((aligned(16))) unsigned short Ks[2][64 * 64];
  __shared__ __attribute__((aligned(16))) unsigned short Vt[2][64 * 64];
  const int tid = threadIdx.x;
  const int lane = tid & 63;
  const int w = tid >> 6;
  const int q5 = lane & 31;
  const int h5 = lane >> 5;
  const int idx = blockIdx.x;
  const int bh = idx & 31;        // 32 consecutive blocks share q-tile -> dist L2 reuse
  const int qt = idx >> 5;
  const int b = bh >> 4, h = bh & 15;
  const int qrow0 = qt * 128 + w * 32;
  const float g2 = gamma[bh] * LOG2E;

  const size_t base = (size_t)bh * SEQ * HD;      // q,k: [bh][n][d]
  const size_t vtbase = (size_t)bh * HD * SEQ;    // vt:  [bh][d][n]

  // Q fragments (B-operand of 32x32x16: col q=lane&31, k=ks*16+h5*8+e)
  bf16x8 qf[4];
  #pragma unroll
  for (int ks = 0; ks < 4; ++ks)
    qf[ks] = *reinterpret_cast<const bf16x8*>(
        &qb[base + (size_t)(qrow0 + q5) * HD + ks * 16 + h5 * 8]);

  // per-lane dist row pointer (q-row fixed per lane; +4*h5 folded in)
  const float* drow = dist + (size_t)(qrow0 + q5) * SEQ + 4 * h5;

  // O^T accumulators: o[db], d = db*32 + (reg&3)+8*(reg>>2)+4*h5, col q=q5
  f32x16 o[2];
  #pragma unroll
  for (int i = 0; i < 16; ++i) { o[0][i] = 0.f; o[1][i] = 0.f; }
  float m_run = -INFINITY;
  float l_run = 0.f;

  // staging: pre-swizzled global source, linear LDS dest (rule #21)
  const int srow = tid >> 3;                       // 0..31
  const int schunk = (tid & 7) ^ (srow & 7);       // 16B chunk in source row
  const unsigned short* ksrc0 = kb + base + (size_t)srow * HD + schunk * 8;
  const unsigned short* ksrc1 = ksrc0 + (size_t)32 * HD;
  const unsigned short* vsrc0 = vtb + vtbase + (size_t)srow * SEQ + schunk * 8;
  const unsigned short* vsrc1 = vsrc0 + (size_t)32 * SEQ;

  // prologue: stage K(0),V(0) -> buf0 and K(1) -> buf1
  GL16(ksrc0, &Ks[0][w * 512]);
  GL16(ksrc1, &Ks[0][2048 + w * 512]);
  GL16(vsrc0, &Vt[0][w * 512]);
  GL16(vsrc1, &Vt[0][2048 + w * 512]);
  GL16(ksrc0 + (size_t)64 * HD, &Ks[1][w * 512]);
  GL16(ksrc1 + (size_t)64 * HD, &Ks[1][2048 + w * 512]);
  __syncthreads();

  f32x16 sA[2], sB[2];

  // QK(0) -> sA (from Ks[0])
  #pragma unroll
  for (int i = 0; i < 16; ++i) { sA[0][i] = 0.f; sA[1][i] = 0.f; }
  __builtin_amdgcn_s_setprio(1);
  #pragma unroll
  for (int blk = 0; blk < 2; ++blk)
    #pragma unroll
    for (int ks = 0; ks < 4; ++ks) {
      bf16x8 kf = *reinterpret_cast<const bf16x8*>(
          &Ks[0][(blk * 32 + q5) * 64 + ((ks * 2 + h5) ^ (q5 & 7)) * 8]);
      sA[blk] = __builtin_amdgcn_mfma_f32_32x32x16_bf16(kf, qf[ks], sA[blk], 0, 0, 0);
    }
  __builtin_amdgcn_s_setprio(0);
  __syncthreads();   // all waves finished QK(0) before iter0 overwrites Ks[0] with K(2)

#define ITER(T, CUR, SCUR, SNXT)                                                       \
  {                                                                                    \
    /* dist(T) loads issued early (hidden under QK/stage issue) */                     \
    f32x4 dv[2][4];                                                                    \
    { const float* dp = drow + (T) * 64;                                               \
      _Pragma("unroll")                                                                \
      for (int blk = 0; blk < 2; ++blk)                                                \
        _Pragma("unroll")                                                              \
        for (int rp = 0; rp < 4; ++rp)                                                 \
          dv[blk][rp] = *reinterpret_cast<const f32x4*>(dp + 32 * blk + 8 * rp);       \
    }                                                                                  \
    /* QK(T+1) -> SNXT from Ks[CUR^1]; result consumed next iter (non-blocking) */     \
    if ((T) + 1 < NT) {                                                                \
      _Pragma("unroll")                                                                \
      for (int i = 0; i < 16; ++i) { SNXT[0][i] = 0.f; SNXT[1][i] = 0.f; }             \
      __builtin_amdgcn_s_setprio(1);                                                   \
      _Pragma("unroll")                                                                \
      for (int blk = 0; blk < 2; ++blk)                                                \
        _Pragma("unroll")                                                              \
        for (int ks = 0; ks < 4; ++ks) {                                               \
          bf16x8 kf = *reinterpret_cast<const bf16x8*>(                                \
              &Ks[(CUR) ^ 1][(blk * 32 + q5) * 64 + ((ks * 2 + h5) ^ (q5 & 7)) * 8]);  \
          SNXT[blk] = __builtin_amdgcn_mfma_f32_32x32x16_bf16(kf, qf[ks], SNXT[blk], 0, 0, 0); \
        }                                                                              \
      __builtin_amdgcn_s_setprio(0);                                                   \
    }                                                                                  \
    /* stage K(T+2) -> Ks[CUR] (K(T) consumed last iter), V(T+1) -> Vt[CUR^1] */       \
    if ((T) + 2 < NT) {                                                                \
      const size_t m2 = (size_t)((T) + 2) * 64;                                        \
      GL16(ksrc0 + m2 * HD, &Ks[CUR][w * 512]);                                        \
      GL16(ksrc1 + m2 * HD, &Ks[CUR][2048 + w * 512]);                                 \
    }                                                                                  \
    if ((T) + 1 < NT) {                                                                \
      const int m1 = ((T) + 1) * 64;                                                   \
      GL16(vsrc0 + m1, &Vt[(CUR) ^ 1][w * 512]);                                       \
      GL16(vsrc1 + m1, &Vt[(CUR) ^ 1][2048 + w * 512]);                                \
    }                                                                                  \
    /* softmax(T) on SCUR (VALU; overlaps in-flight QK MFMAs) */                       \
    float mx[8];                                                                       \
    _Pragma("unroll")                                                                  \
    for (int blk = 0; blk < 2; ++blk)                                                  \
      _Pragma("unroll")                                                                \
      for (int rp = 0; rp < 4; ++rp) {                                                 \
        float v0 = __builtin_fmaf(-g2, dv[blk][rp][0], SCUR[blk][rp * 4 + 0]);         \
        float v1 = __builtin_fmaf(-g2, dv[blk][rp][1], SCUR[blk][rp * 4 + 1]);         \
        float v2 = __builtin_fmaf(-g2, dv[blk][rp][2], SCUR[blk][rp * 4 + 2]);         \
        float v3 = __builtin_fmaf(-g2, dv[blk][rp][3], SCUR[blk][rp * 4 + 3]);         \
        SCUR[blk][rp * 4 + 0] = v0; SCUR[blk][rp * 4 + 1] = v1;                        \
        SCUR[blk][rp * 4 + 2] = v2; SCUR[blk][rp * 4 + 3] = v3;                        \
        mx[blk * 4 + rp] = fmaxf(fmaxf(v0, v1), fmaxf(v2, v3));                        \
      }                                                                                \
    float pm = fmaxf(fmaxf(fmaxf(mx[0], mx[1]), fmaxf(mx[2], mx[3])),                  \
                     fmaxf(fmaxf(mx[4], mx[5]), fmaxf(mx[6], mx[7])));                 \
    pm = fmaxf(pm, __shfl_xor(pm, 32, 64));                                            \
    if (!__all(pm <= m_run + 8.0f)) {                                                  \
      float mn = fmaxf(m_run, pm);                                                     \
      float corr = exp2f(m_run - mn);                                                  \
      m_run = mn;                                                                      \
      l_run *= corr;                                                                   \
      _Pragma("unroll")                                                                \
      for (int i = 0; i < 16; ++i) { o[0][i] *= corr; o[1][i] *= corr; }               \
    }                                                                                  \
    float psum = 0.f;                                                                  \
    unsigned u[2][4][2];                                                               \
    _Pragma("unroll")                                                                  \
    for (int blk = 0; blk < 2; ++blk)                                                  \
      _Pragma("unroll")                                                                \
      for (int rp = 0; rp < 4; ++rp) {                                                 \
        float p0 = exp2f(SCUR[blk][rp * 4 + 0] - m_run);                               \
        float p1 = exp2f(SCUR[blk][rp * 4 + 1] - m_run);                               \
        float p2 = exp2f(SCUR[blk][rp * 4 + 2] - m_run);                               \
        float p3 = exp2f(SCUR[blk][rp * 4 + 3] - m_run);                               \
        psum += (p0 + p1) + (p2 + p3);                                                 \
        asm("v_cvt_pk_bf16_f32 %0, %1, %2" : "=v"(u[blk][rp][0]) : "v"(p0), "v"(p1));  \
        asm("v_cvt_pk_bf16_f32 %0, %1, %2" : "=v"(u[blk][rp][1]) : "v"(p2), "v"(p3));  \
      }                                                                                \
    psum += __shfl_xor(psum, 32, 64);                                                  \
    l_run += psum;                                                                     \
    unsigned pu[4][4];                                                                 \
    _Pragma("unroll")                                                                  \
    for (int blk = 0; blk < 2; ++blk)                                                  \
      _Pragma("unroll")                                                                \
      for (int jp = 0; jp < 2; ++jp) {                                                 \
        unsigned a0 = u[blk][0][jp], b0 = u[blk][1][jp];                               \
        asm("v_permlane32_swap_b32 %0, %1" : "+v"(a0), "+v"(b0));                      \
        pu[2 * blk][jp] = a0; pu[2 * blk][2 + jp] = b0;                                \
        unsigned a1 = u[blk][2][jp], b1 = u[blk][3][jp];                               \
        asm("v_permlane32_swap_b32 %0, %1" : "+v"(a1), "+v"(b1));                      \
        pu[2 * blk + 1][jp] = a1; pu[2 * blk + 1][2 + jp] = b1;                        \
      }                                                                                \
    /* PV(T) from Vt[CUR] */                                                           \
    __builtin_amdgcn_s_setprio(1);                                                     \
    _Pragma("unroll")                                                                  \
    for (int ks = 0; ks < 4; ++ks) {                                                   \
      u32x4 t_; t_[0] = pu[ks][0]; t_[1] = pu[ks][1]; t_[2] = pu[ks][2]; t_[3] = pu[ks][3]; \
      bf16x8 pf = __builtin_bit_cast(bf16x8, t_);                                      \
      _Pragma("unroll")                                                                \
      for (int db = 0; db < 2; ++db) {                                                 \
        bf16x8 vtf = *reinterpret_cast<const bf16x8*>(                                 \
            &Vt[CUR][(db * 32 + q5) * 64 + ((ks * 2 + h5) ^ (q5 & 7)) * 8]);           \
        o[db] = __builtin_amdgcn_mfma_f32_32x32x16_bf16(vtf, pf, o[db], 0, 0, 0);      \
      }                                                                                \
    }                                                                                  \
    __builtin_amdgcn_s_setprio(0);                                                     \
    __syncthreads();                                                                   \
  }

  for (int mt = 0; mt < NT; mt += 2) {
    ITER(mt, 0, sA, sB)
    ITER(mt + 1, 1, sB, sA)
  }
#undef ITER

  // epilogue: O^T / l, write attn_out [B,N,H*hd] bf16 (8B packed along d)
  {
    float rl = 1.0f / l_run;
    size_t row = (size_t)b * SEQ + qrow0 + q5;
    unsigned short* obase = ab + row * DIM + h * HD + 4 * h5;
    #pragma unroll
    for (int db = 0; db < 2; ++db)
      #pragma unroll
      for (int rp = 0; rp < 4; ++rp) {
        ushort4 w4;
        w4.x = f2bf(o[db][rp * 4 + 0] * rl);
        w4.y = f2bf(o[db][rp * 4 + 1] * rl);
        w4.z = f2bf(o[db][rp * 4 + 2] * rl);
        w4.w = f2bf(o[db][rp * 4 + 3] * rl);
        *reinterpret_cast<ushort4*>(&obase[db * 32 + 8 * rp]) = w4;
      }
  }
}

extern "C" void kernel_launch(void* const* d_in, const int* in_sizes, int n_in,
                              void* d_out, int out_size, void* d_ws, size_t ws_size,
                              hipStream_t stream) {
  const float* x     = (const float*)d_in[0];
  const float* gamma = (const float*)d_in[1];
  const float* dist  = (const float*)d_in[2];
  const float* Wqkv  = (const float*)d_in[3];
  const float* bqkv  = (const float*)d_in[4];
  const float* Wproj = (const float*)d_in[5];
  const float* bproj = (const float*)d_in[6];
  float* out = (float*)d_out;

  char* ws = (char*)d_ws;
  unsigned short* xb     = (unsigned short*)(ws);                 // 8,388,608 B
  unsigned short* wqkvt  = (unsigned short*)(ws + 8388608);       // 6,291,456 B
  unsigned short* wprojt = (unsigned short*)(ws + 14680064);      // 2,097,152 B
  unsigned short* qbuf   = (unsigned short*)(ws + 16777216);      // [B,H,N,hd] (q pre-scaled)
  unsigned short* kbuf   = (unsigned short*)(ws + 25165824);      // [B,H,N,hd]
  unsigned short* vtbuf  = (unsigned short*)(ws + 33554432);      // [B,H,hd,N] (transposed)
  unsigned short* abuf   = (unsigned short*)(ws + 41943040);      // [B,N,DIM]

  convert_x<<<4096, 256, 0, stream>>>(x, xb, (BATCH * SEQ * DIM) / 4);
  transpose_convert<<<dim3(96, 32), dim3(32, 8), 0, stream>>>(Wqkv, wqkvt, DIM, 3 * DIM);
  transpose_convert<<<dim3(32, 32), dim3(32, 8), 0, stream>>>(Wproj, wprojt, DIM, DIM);
  // QKV: [4096,1024] x [1024,3072]
  gemm128<<<dim3(24, 32), 256, 0, stream>>>(xb, wqkvt, bqkv, DIM, 0, qbuf, kbuf, vtbuf, nullptr);
  // attention: 16 q-tiles x 32 bh, T15 pipelined
  attn_kernel<<<(SEQ / 128) * BATCH * NH, 256, 0, stream>>>(qbuf, kbuf, vtbuf, gamma, dist, abuf);
  // proj: [4096,1024] x [1024,1024]
  gemm128<<<dim3(8, 32), 256, 0, stream>>>(abuf, wprojt, bproj, DIM, 1, nullptr, nullptr, nullptr, out);
}

// Round 9
// 167.911 us; speedup vs baseline: 1.0436x; 1.0436x over previous
//
#include <hip/hip_runtime.h>
#include <cstdint>
#include <cstddef>

#define HD 64
#define NH 16
#define BATCH 2
#define SEQ 2048
#define DIM 1024
#define SCALE 0.03125f   // 1024^-0.5
#define LOG2E 1.4426950408889634f
#define QSCALE (SCALE * LOG2E)   // folded into q at QKV epilogue
#define NT (SEQ / 64)             // 32 KV tiles

typedef short bf16x8 __attribute__((ext_vector_type(8)));
typedef float f32x4 __attribute__((ext_vector_type(4)));
typedef float f32x16 __attribute__((ext_vector_type(16)));
typedef unsigned u32x4 __attribute__((ext_vector_type(4)));

// global_load_lds, 16B per lane; LDS dest = wave-uniform base + lane*16
#define GL16(gp, lp) __builtin_amdgcn_global_load_lds( \
    (const __attribute__((address_space(1))) unsigned int*)(gp), \
    (__attribute__((address_space(3))) unsigned int*)(lp), 16, 0, 0)

static __device__ __forceinline__ unsigned short f2bf(float f) {
  union { float f; unsigned u; } a; a.f = f;
  unsigned r = a.u + 0x7fffu + ((a.u >> 16) & 1u);  // RNE
  return (unsigned short)(r >> 16);
}

static __device__ __forceinline__ f32x4 zero4() {
  f32x4 z; z[0] = 0.f; z[1] = 0.f; z[2] = 0.f; z[3] = 0.f; return z;
}

// ---------------- fp32 -> bf16 convert (vectorized) ----------------
__global__ void convert_x(const float* __restrict__ in, unsigned short* __restrict__ out, int n4) {
  int i = blockIdx.x * blockDim.x + threadIdx.x;
  if (i < n4) {
    float4 v = reinterpret_cast<const float4*>(in)[i];
    ushort4 o;
    o.x = f2bf(v.x); o.y = f2bf(v.y); o.z = f2bf(v.z); o.w = f2bf(v.w);
    reinterpret_cast<ushort4*>(out)[i] = o;
  }
}

// ---------------- transpose + convert: in[R][C] fp32 -> out[C][R] bf16 ----------------
__global__ void transpose_convert(const float* __restrict__ in, unsigned short* __restrict__ out,
                                  int R, int C) {
  __shared__ float tile[32][33];
  int bx = blockIdx.x * 32;
  int by = blockIdx.y * 32;
  int tx = threadIdx.x, ty = threadIdx.y;  // block (32,8)
  #pragma unroll
  for (int i = 0; i < 32; i += 8)
    tile[ty + i][tx] = in[(size_t)(by + ty + i) * C + bx + tx];
  __syncthreads();
  #pragma unroll
  for (int i = 0; i < 32; i += 8)
    out[(size_t)(bx + ty + i) * R + by + tx] = f2bf(tile[tx][ty + i]);
}

// ------- GEMM 128x128 tile (m97-style, global_load_lds): C = A * Bt^T --------
// mode 0: scatter epilogue into q (pre-scaled)/k [B,H,N,hd] and v TRANSPOSED [B,H,hd,N]
// mode 1: fp32 epilogue into outf [M][DIM] (+bias)
__global__ __launch_bounds__(256) void gemm128(
    const unsigned short* __restrict__ A, const unsigned short* __restrict__ Bt,
    const float* __restrict__ bias, int K, int mode,
    unsigned short* __restrict__ qo, unsigned short* __restrict__ ko,
    unsigned short* __restrict__ vo, float* __restrict__ outf) {
  __shared__ __attribute__((aligned(16))) unsigned short As[128 * 64];
  __shared__ __attribute__((aligned(16))) unsigned short Bs[128 * 64];
  const int tid = threadIdx.x;
  const int lane = tid & 63, w = tid >> 6;
  const int lo = lane & 15, hi = lane >> 4;
  const int wm = w >> 1, wn = w & 1;
  // XCD-aware swizzle (T1): nwg % 8 == 0 for both call sites
  const int gx = gridDim.x;
  const int nwg = gx * gridDim.y;
  const int flat = blockIdx.y * gx + blockIdx.x;
  const int swz = (flat & 7) * (nwg >> 3) + (flat >> 3);
  const int m0 = (swz / gx) * 128, n0 = (swz % gx) * 128;
  const int srow = tid >> 3, scol = (tid & 7) * 8;
  const unsigned short* abase = A + (size_t)(m0 + srow) * K + scol;
  const unsigned short* bbase = Bt + (size_t)(n0 + srow) * K + scol;

  f32x4 acc[4][4];
  #pragma unroll
  for (int mr = 0; mr < 4; ++mr)
    #pragma unroll
    for (int nr = 0; nr < 4; ++nr) acc[mr][nr] = zero4();

  const int nkt = K / 64;
  for (int kt = 0; kt < nkt; ++kt) {
    const unsigned short* ak = abase + kt * 64;
    const unsigned short* bk = bbase + kt * 64;
    #pragma unroll
    for (int i = 0; i < 4; ++i) {
      GL16(ak + (size_t)(32 * i) * K, &As[(w * 64 + 256 * i) * 8]);
      GL16(bk + (size_t)(32 * i) * K, &Bs[(w * 64 + 256 * i) * 8]);
    }
    __syncthreads();
    __builtin_amdgcn_s_setprio(1);
    #pragma unroll
    for (int kc = 0; kc < 2; ++kc) {
      bf16x8 af[4], bfr[4];
      #pragma unroll
      for (int mr = 0; mr < 4; ++mr)
        af[mr] = *reinterpret_cast<const bf16x8*>(
            &As[(wm * 64 + mr * 16 + lo) * 64 + kc * 32 + hi * 8]);
      #pragma unroll
      for (int nr = 0; nr < 4; ++nr)
        bfr[nr] = *reinterpret_cast<const bf16x8*>(
            &Bs[(wn * 64 + nr * 16 + lo) * 64 + kc * 32 + hi * 8]);
      #pragma unroll
      for (int mr = 0; mr < 4; ++mr)
        #pragma unroll
        for (int nr = 0; nr < 4; ++nr)
          acc[mr][nr] = __builtin_amdgcn_mfma_f32_16x16x32_bf16(af[mr], bfr[nr], acc[mr][nr], 0, 0, 0);
    }
    __builtin_amdgcn_s_setprio(0);
    __syncthreads();
  }

  #pragma unroll
  for (int nr = 0; nr < 4; ++nr) {
    const int gcol = n0 + wn * 64 + nr * 16 + lo;
    const float bv = bias[gcol];
    #pragma unroll
    for (int mr = 0; mr < 4; ++mr)
      #pragma unroll
      for (int j = 0; j < 4; ++j) {
        const int grow = m0 + wm * 64 + mr * 16 + hi * 4 + j;
        float val = acc[mr][nr][j] + bv;
        if (mode == 0) {
          int which = gcol >> 10;         // 0=q 1=k 2=v
          int hh = (gcol >> 6) & 15;
          int d = gcol & 63;
          int bb = grow >> 11;
          int n = grow & 2047;
          if (which == 0) {
            qo[((size_t)(bb * NH + hh) * SEQ + n) * HD + d] = f2bf(val * QSCALE);
          } else if (which == 1) {
            ko[((size_t)(bb * NH + hh) * SEQ + n) * HD + d] = f2bf(val);
          } else {
            vo[((size_t)(bb * NH + hh) * HD + d) * SEQ + n] = f2bf(val);  // [B,H,hd,N]
          }
        } else {
          outf[(size_t)grow * DIM + gcol] = val;
        }
      }
  }
}

// ------- flash attention, 32x32 MFMA, counted-vmcnt dual-barrier schedule (T3/T4) ------
// grid: (SEQ/128) * B*H = 512 blocks; block 256 threads (4 waves, 32 q-rows each).
// Per tile t:  vmcnt(2)+bar  [K(t) ready, V(t) stays in flight]
//              dist(t) -> issue K(t+1) -> QK(t) -> softmax(t)
//              vmcnt(2)+bar  [V(t) ready, K(t+1) stays in flight]
//              issue V(t+1) -> PV(t)
// vmcnt never drains to 0 in the main loop (the R8 __syncthreads drain was the stall).
__global__ __launch_bounds__(256, 2) void attn_kernel(
    const unsigned short* __restrict__ qb, const unsigned short* __restrict__ kb,
    const unsigned short* __restrict__ vtb, const float* __restrict__ gamma,
    const float* __restrict__ dist, unsigned short* __restrict__ ab) {
  // K/V tiles: XOR-swizzled layout, 128B rows, double-buffered (32 KiB total).
  __shared__ __attribute__((aligned(16))) unsigned short Ks[2][64 * 64];
  __shared__ __attribute__((aligned(16))) unsigned short Vt[2][64 * 64];
  const int tid = threadIdx.x;
  const int lane = tid & 63;
  const int w = tid >> 6;
  const int q5 = lane & 31;
  const int h5 = lane >> 5;
  const int idx = blockIdx.x;
  const int bh = idx & 31;        // same-bh blocks differ by 32 -> same XCD -> K/V L2 reuse
  const int qt = idx >> 5;
  const int b = bh >> 4, h = bh & 15;
  const int qrow0 = qt * 128 + w * 32;
  const float g2 = gamma[bh] * LOG2E;

  const size_t base = (size_t)bh * SEQ * HD;      // q,k: [bh][n][d]
  const size_t vtbase = (size_t)bh * HD * SEQ;    // vt:  [bh][d][n]

  // Q fragments (B-operand of 32x32x16: col q=lane&31, k=ks*16+h5*8+e)
  bf16x8 qf[4];
  #pragma unroll
  for (int ks = 0; ks < 4; ++ks)
    qf[ks] = *reinterpret_cast<const bf16x8*>(
        &qb[base + (size_t)(qrow0 + q5) * HD + ks * 16 + h5 * 8]);

  // per-lane dist row pointer (q-row fixed per lane; +4*h5 folded in)
  const float* drow = dist + (size_t)(qrow0 + q5) * SEQ + 4 * h5;

  // O^T accumulators: o[db], d = db*32 + (reg&3)+8*(reg>>2)+4*h5, col q=q5
  f32x16 o[2];
  #pragma unroll
  for (int i = 0; i < 16; ++i) { o[0][i] = 0.f; o[1][i] = 0.f; }
  float m_run = -INFINITY;
  float l_run = 0.f;

  // staging: pre-swizzled global source, linear LDS dest (rule #21)
  const int srow = tid >> 3;                       // 0..31
  const int schunk = (tid & 7) ^ (srow & 7);       // 16B chunk in source row
  const unsigned short* ksrc0 = kb + base + (size_t)srow * HD + schunk * 8;
  const unsigned short* ksrc1 = ksrc0 + (size_t)32 * HD;
  const unsigned short* vsrc0 = vtb + vtbase + (size_t)srow * SEQ + schunk * 8;
  const unsigned short* vsrc1 = vsrc0 + (size_t)32 * SEQ;

  // prologue: issue K(0) then V(0) (K pair before V pair -> steady-state vmcnt counts)
  GL16(ksrc0, &Ks[0][w * 512]);
  GL16(ksrc1, &Ks[0][2048 + w * 512]);
  GL16(vsrc0, &Vt[0][w * 512]);
  GL16(vsrc1, &Vt[0][2048 + w * 512]);

#define ITER(T, CUR)                                                                   \
  {                                                                                    \
    /* K(T) ready (drains all but the newest 2 = V(T)); barrier for LDS visibility */  \
    asm volatile("s_waitcnt vmcnt(2)" ::: "memory");                                   \
    __builtin_amdgcn_s_barrier();                                                      \
    /* dist(T) loads first (their auto-wait then leaves K(T+1) in flight) */           \
    f32x4 dv[2][4];                                                                    \
    { const float* dp = drow + (T) * 64;                                               \
      _Pragma("unroll")                                                                \
      for (int blk = 0; blk < 2; ++blk)                                                \
        _Pragma("unroll")                                                              \
        for (int rp = 0; rp < 4; ++rp)                                                 \
          dv[blk][rp] = *reinterpret_cast<const f32x4*>(dp + 32 * blk + 8 * rp);       \
    }                                                                                  \
    /* issue K(T+1) -> other K buffer (its readers retired at this iter's barrier) */  \
    if ((T) + 1 < NT) {                                                                \
      const size_t m1 = (size_t)((T) + 1) * 64;                                        \
      GL16(ksrc0 + m1 * HD, &Ks[(CUR) ^ 1][w * 512]);                                  \
      GL16(ksrc1 + m1 * HD, &Ks[(CUR) ^ 1][2048 + w * 512]);                           \
    }                                                                                  \
    /* QK(T) from Ks[CUR] */                                                           \
    f32x16 s[2];                                                                       \
    _Pragma("unroll")                                                                  \
    for (int i = 0; i < 16; ++i) { s[0][i] = 0.f; s[1][i] = 0.f; }                     \
    __builtin_amdgcn_s_setprio(1);                                                     \
    _Pragma("unroll")                                                                  \
    for (int blk = 0; blk < 2; ++blk)                                                  \
      _Pragma("unroll")                                                                \
      for (int ks = 0; ks < 4; ++ks) {                                                 \
        bf16x8 kf = *reinterpret_cast<const bf16x8*>(                                  \
            &Ks[CUR][(blk * 32 + q5) * 64 + ((ks * 2 + h5) ^ (q5 & 7)) * 8]);          \
        s[blk] = __builtin_amdgcn_mfma_f32_32x32x16_bf16(kf, qf[ks], s[blk], 0, 0, 0); \
      }                                                                                \
    __builtin_amdgcn_s_setprio(0);                                                     \
    /* softmax(T): bias, max, defer-max, exp, sum, pack */                             \
    float mx[8];                                                                       \
    _Pragma("unroll")                                                                  \
    for (int blk = 0; blk < 2; ++blk)                                                  \
      _Pragma("unroll")                                                                \
      for (int rp = 0; rp < 4; ++rp) {                                                 \
        float v0 = __builtin_fmaf(-g2, dv[blk][rp][0], s[blk][rp * 4 + 0]);            \
        float v1 = __builtin_fmaf(-g2, dv[blk][rp][1], s[blk][rp * 4 + 1]);            \
        float v2 = __builtin_fmaf(-g2, dv[blk][rp][2], s[blk][rp * 4 + 2]);            \
        float v3 = __builtin_fmaf(-g2, dv[blk][rp][3], s[blk][rp * 4 + 3]);            \
        s[blk][rp * 4 + 0] = v0; s[blk][rp * 4 + 1] = v1;                              \
        s[blk][rp * 4 + 2] = v2; s[blk][rp * 4 + 3] = v3;                              \
        mx[blk * 4 + rp] = fmaxf(fmaxf(v0, v1), fmaxf(v2, v3));                        \
      }                                                                                \
    float pm = fmaxf(fmaxf(fmaxf(mx[0], mx[1]), fmaxf(mx[2], mx[3])),                  \
                     fmaxf(fmaxf(mx[4], mx[5]), fmaxf(mx[6], mx[7])));                 \
    pm = fmaxf(pm, __shfl_xor(pm, 32, 64));                                            \
    if (!__all(pm <= m_run + 8.0f)) {                                                  \
      float mn = fmaxf(m_run, pm);                                                     \
      float corr = exp2f(m_run - mn);                                                  \
      m_run = mn;                                                                      \
      l_run *= corr;                                                                   \
      _Pragma("unroll")                                                                \
      for (int i = 0; i < 16; ++i) { o[0][i] *= corr; o[1][i] *= corr; }               \
    }                                                                                  \
    float psum = 0.f;                                                                  \
    unsigned u[2][4][2];                                                               \
    _Pragma("unroll")                                                                  \
    for (int blk = 0; blk < 2; ++blk)                                                  \
      _Pragma("unroll")                                                                \
      for (int rp = 0; rp < 4; ++rp) {                                                 \
        float p0 = exp2f(s[blk][rp * 4 + 0] - m_run);                                  \
        float p1 = exp2f(s[blk][rp * 4 + 1] - m_run);                                  \
        float p2 = exp2f(s[blk][rp * 4 + 2] - m_run);                                  \
        float p3 = exp2f(s[blk][rp * 4 + 3] - m_run);                                  \
        psum += (p0 + p1) + (p2 + p3);                                                 \
        asm("v_cvt_pk_bf16_f32 %0, %1, %2" : "=v"(u[blk][rp][0]) : "v"(p0), "v"(p1));  \
        asm("v_cvt_pk_bf16_f32 %0, %1, %2" : "=v"(u[blk][rp][1]) : "v"(p2), "v"(p3));  \
      }                                                                                \
    psum += __shfl_xor(psum, 32, 64);                                                  \
    l_run += psum;                                                                     \
    unsigned pu[4][4];                                                                 \
    _Pragma("unroll")                                                                  \
    for (int blk = 0; blk < 2; ++blk)                                                  \
      _Pragma("unroll")                                                                \
      for (int jp = 0; jp < 2; ++jp) {                                                 \
        unsigned a0 = u[blk][0][jp], b0 = u[blk][1][jp];                               \
        asm("v_permlane32_swap_b32 %0, %1" : "+v"(a0), "+v"(b0));                      \
        pu[2 * blk][jp] = a0; pu[2 * blk][2 + jp] = b0;                                \
        unsigned a1 = u[blk][2][jp], b1 = u[blk][3][jp];                               \
        asm("v_permlane32_swap_b32 %0, %1" : "+v"(a1), "+v"(b1));                      \
        pu[2 * blk + 1][jp] = a1; pu[2 * blk + 1][2 + jp] = b1;                        \
      }                                                                                \
    /* V(T) ready (drains all but newest 2 = K(T+1); last iter: drain all) */          \
    if ((T) + 1 < NT)                                                                  \
      asm volatile("s_waitcnt vmcnt(2)" ::: "memory");                                 \
    else                                                                               \
      asm volatile("s_waitcnt vmcnt(0)" ::: "memory");                                 \
    __builtin_amdgcn_s_barrier();                                                      \
    /* issue V(T+1) -> other V buffer (readers retired at the barrier above) */        \
    if ((T) + 1 < NT) {                                                                \
      const int m1 = ((T) + 1) * 64;                                                   \
      GL16(vsrc0 + m1, &Vt[(CUR) ^ 1][w * 512]);                                       \
      GL16(vsrc1 + m1, &Vt[(CUR) ^ 1][2048 + w * 512]);                                \
    }                                                                                  \
    /* PV(T) from Vt[CUR] */                                                           \
    __builtin_amdgcn_s_setprio(1);                                                     \
    _Pragma("unroll")                                                                  \
    for (int ks = 0; ks < 4; ++ks) {                                                   \
      u32x4 t_; t_[0] = pu[ks][0]; t_[1] = pu[ks][1]; t_[2] = pu[ks][2]; t_[3] = pu[ks][3]; \
      bf16x8 pf = __builtin_bit_cast(bf16x8, t_);                                      \
      _Pragma("unroll")                                                                \
      for (int db = 0; db < 2; ++db) {                                                 \
        bf16x8 vtf = *reinterpret_cast<const bf16x8*>(                                 \
            &Vt[CUR][(db * 32 + q5) * 64 + ((ks * 2 + h5) ^ (q5 & 7)) * 8]);           \
        o[db] = __builtin_amdgcn_mfma_f32_32x32x16_bf16(vtf, pf, o[db], 0, 0, 0);      \
      }                                                                                \
    }                                                                                  \
    __builtin_amdgcn_s_setprio(0);                                                     \
  }

  for (int mt = 0; mt < NT; mt += 2) {
    ITER(mt, 0)
    ITER(mt + 1, 1)
  }
#undef ITER

  // epilogue: O^T / l, write attn_out [B,N,H*hd] bf16 (8B packed along d)
  {
    float rl = 1.0f / l_run;
    size_t row = (size_t)b * SEQ + qrow0 + q5;
    unsigned short* obase = ab + row * DIM + h * HD + 4 * h5;
    #pragma unroll
    for (int db = 0; db < 2; ++db)
      #pragma unroll
      for (int rp = 0; rp < 4; ++rp) {
        ushort4 w4;
        w4.x = f2bf(o[db][rp * 4 + 0] * rl);
        w4.y = f2bf(o[db][rp * 4 + 1] * rl);
        w4.z = f2bf(o[db][rp * 4 + 2] * rl);
        w4.w = f2bf(o[db][rp * 4 + 3] * rl);
        *reinterpret_cast<ushort4*>(&obase[db * 32 + 8 * rp]) = w4;
      }
  }
}

extern "C" void kernel_launch(void* const* d_in, const int* in_sizes, int n_in,
                              void* d_out, int out_size, void* d_ws, size_t ws_size,
                              hipStream_t stream) {
  const float* x     = (const float*)d_in[0];
  const float* gamma = (const float*)d_in[1];
  const float* dist  = (const float*)d_in[2];
  const float* Wqkv  = (const float*)d_in[3];
  const float* bqkv  = (const float*)d_in[4];
  const float* Wproj = (const float*)d_in[5];
  const float* bproj = (const float*)d_in[6];
  float* out = (float*)d_out;

  char* ws = (char*)d_ws;
  unsigned short* xb     = (unsigned short*)(ws);                 // 8,388,608 B
  unsigned short* wqkvt  = (unsigned short*)(ws + 8388608);       // 6,291,456 B
  unsigned short* wprojt = (unsigned short*)(ws + 14680064);      // 2,097,152 B
  unsigned short* qbuf   = (unsigned short*)(ws + 16777216);      // [B,H,N,hd] (q pre-scaled)
  unsigned short* kbuf   = (unsigned short*)(ws + 25165824);      // [B,H,N,hd]
  unsigned short* vtbuf  = (unsigned short*)(ws + 33554432);      // [B,H,hd,N] (transposed)
  unsigned short* abuf   = (unsigned short*)(ws + 41943040);      // [B,N,DIM]

  convert_x<<<4096, 256, 0, stream>>>(x, xb, (BATCH * SEQ * DIM) / 4);
  transpose_convert<<<dim3(96, 32), dim3(32, 8), 0, stream>>>(Wqkv, wqkvt, DIM, 3 * DIM);
  transpose_convert<<<dim3(32, 32), dim3(32, 8), 0, stream>>>(Wproj, wprojt, DIM, DIM);
  // QKV: [4096,1024] x [1024,3072]
  gemm128<<<dim3(24, 32), 256, 0, stream>>>(xb, wqkvt, bqkv, DIM, 0, qbuf, kbuf, vtbuf, nullptr);
  // attention: 16 q-tiles x 32 bh, counted-vmcnt dual-barrier schedule
  attn_kernel<<<(SEQ / 128) * BATCH * NH, 256, 0, stream>>>(qbuf, kbuf, vtbuf, gamma, dist, abuf);
  // proj: [4096,1024] x [1024,1024]
  gemm128<<<dim3(8, 32), 256, 0, stream>>>(abuf, wprojt, bproj, DIM, 1, nullptr, nullptr, nullptr, out);
}